// Round 1
// baseline (25.500 us; speedup 1.0000x reference)
//
#include <hip/hip_runtime.h>
#include <hip/hip_bf16.h>

#define F 26
#define A 7
#define DIM 16
#define BATCH 4096
#define TV 2083764

__device__ __constant__ int c_FIELD_DIMS[F] = {
    1000000, 500000, 250000, 100000, 100000, 50000, 50000, 10000, 10000,
    5000, 5000, 1000, 1000, 500, 500, 200, 200, 100, 100, 50, 50, 20, 20,
    10, 10, 4};
__device__ __constant__ int c_OFFSETS[F] = {
    0, 1000000, 1500000, 1750000, 1850000, 1950000, 2000000, 2050000,
    2060000, 2070000, 2075000, 2080000, 2081000, 2082000, 2082500, 2083000,
    2083200, 2083400, 2083500, 2083600, 2083650, 2083700, 2083720, 2083740,
    2083750, 2083760};
__device__ __constant__ int c_ACTION[A] = {1, 64, 128, 256, 512, 1024, 2048};

// Block: 256 threads = 4 waves; one wave per batch element.
// Wave layout: lane = fg*16 + d  (fg in 0..3 handles fields f = fg, fg+4, ...;
// d in 0..15 is the embedding dim).
__global__ __launch_bounds__(256, 4) void gsq_fm_kernel(
    const int* __restrict__ x,            // (B, F)
    const float* __restrict__ emb_table,  // (TV, 16)
    const float* __restrict__ lin_w,      // (TV, 1)
    const float* __restrict__ lin_bias,   // (1,)
    const float* __restrict__ codebooks,  // (6, F, 2048, 16)
    const int* __restrict__ assignments,  // (6, TV)
    const float* __restrict__ arch,       // (F, A)
    const float* __restrict__ gumbel,     // (F, A)
    float* __restrict__ out)              // (B,)
{
    __shared__ float probs_s[F][A];

    const int t = threadIdx.x;

    // ---- per-block probs computation (26 threads, trivial) ----
    if (t < F) {
        const int dims = c_FIELD_DIMS[t];
        float z[A];
        float m = -1e30f;
        for (int k = 0; k < A; ++k) {
            bool allowed = (k == 0) ? (dims < 150)
                                    : (5 * c_ACTION[k] <= 2 * dims);
            float logit = allowed ? arch[t * A + k] : -1e9f;
            z[k] = logit + gumbel[t * A + k];  // TEMPERATURE == 1
            m = fmaxf(m, z[k]);
        }
        float ssum = 0.f;
        for (int k = 0; k < A; ++k) {
            z[k] = expf(z[k] - m);  // disallowed -> exp(-1e9) == 0.0f exactly
            ssum += z[k];
        }
        const float inv = 1.f / ssum;
        for (int k = 0; k < A; ++k) probs_s[t][k] = z[k] * inv;
    }
    __syncthreads();

    const int lane = t & 63;
    const int fg = lane >> 4;   // field group 0..3
    const int d = lane & 15;    // dim 0..15
    const int b = blockIdx.x * 4 + (t >> 6);

    float s_acc = 0.f;   // sum_f x_emb[b,f,d]   (partial over this fg's fields)
    float q_acc = 0.f;   // sum_f x_emb[b,f,d]^2 (partial)
    float lin_acc = 0.f; // sum_f lin_w[gid]     (partial, d==0 lanes only)

    for (int f = fg; f < F; f += 4) {
        const int gid = x[b * F + f] + c_OFFSETS[f];

        float xe = 0.f;
        const float p0 = probs_s[f][0];
        if (p0 != 0.f) {  // only 9 small fields use the full emb table
            xe = p0 * emb_table[gid * DIM + d];
        }
        // allowed codebook actions form a prefix; probs are exactly 0 beyond it
        for (int a = 0; a < 6; ++a) {
            const float p = probs_s[f][a + 1];
            if (p == 0.f) break;
            const int code = assignments[a * TV + gid];
            xe = fmaf(p, codebooks[(((a * F) + f) * 2048 + code) * DIM + d], xe);
        }
        s_acc += xe;
        q_acc = fmaf(xe, xe, q_acc);
        if (d == 0) lin_acc += lin_w[gid];
    }

    // ---- reductions (register-only, shfl butterflies) ----
    // sum s,q across the 4 field-groups (lanes differing in bits 4,5)
    s_acc += __shfl_xor(s_acc, 16, 64);
    s_acc += __shfl_xor(s_acc, 32, 64);
    q_acc += __shfl_xor(q_acc, 16, 64);
    q_acc += __shfl_xor(q_acc, 32, 64);

    float val = s_acc * s_acc - q_acc;  // identical across the 4 fg copies
    val += __shfl_xor(val, 1, 64);
    val += __shfl_xor(val, 2, 64);
    val += __shfl_xor(val, 4, 64);
    val += __shfl_xor(val, 8, 64);

    // lin: sum across all 64 lanes (only d==0 lanes contributed)
    lin_acc += __shfl_xor(lin_acc, 1, 64);
    lin_acc += __shfl_xor(lin_acc, 2, 64);
    lin_acc += __shfl_xor(lin_acc, 4, 64);
    lin_acc += __shfl_xor(lin_acc, 8, 64);
    lin_acc += __shfl_xor(lin_acc, 16, 64);
    lin_acc += __shfl_xor(lin_acc, 32, 64);

    if (lane == 0) {
        out[b] = lin_acc + lin_bias[0] + 0.5f * val;
    }
}

extern "C" void kernel_launch(void* const* d_in, const int* in_sizes, int n_in,
                              void* d_out, int out_size, void* d_ws, size_t ws_size,
                              hipStream_t stream) {
    const int*   x           = (const int*)d_in[0];
    const float* emb_table   = (const float*)d_in[1];
    const float* lin_w       = (const float*)d_in[2];
    const float* lin_bias    = (const float*)d_in[3];
    const float* codebooks   = (const float*)d_in[4];
    const int*   assignments = (const int*)d_in[5];
    const float* arch        = (const float*)d_in[6];
    const float* gumbel      = (const float*)d_in[7];
    float* out = (float*)d_out;

    dim3 grid(BATCH / 4);   // 4 batch elements (waves) per block
    dim3 block(256);
    hipLaunchKernelGGL(gsq_fm_kernel, grid, block, 0, stream,
                       x, emb_table, lin_w, lin_bias, codebooks, assignments,
                       arch, gumbel, out);
}

// Round 2
// 17.424 us; speedup vs baseline: 1.4635x; 1.4635x over previous
//
#include <hip/hip_runtime.h>
#include <hip/hip_bf16.h>

#define F 26
#define FPAD 28
#define A 7
#define DIM 16
#define BATCH 4096
#define TV 2083764

__device__ __constant__ int c_FIELD_DIMS[F] = {
    1000000, 500000, 250000, 100000, 100000, 50000, 50000, 10000, 10000,
    5000, 5000, 1000, 1000, 500, 500, 200, 200, 100, 100, 50, 50, 20, 20,
    10, 10, 4};
__device__ __constant__ int c_OFFSETS[F] = {
    0, 1000000, 1500000, 1750000, 1850000, 1950000, 2000000, 2050000,
    2060000, 2070000, 2075000, 2080000, 2081000, 2082000, 2082500, 2083000,
    2083200, 2083400, 2083500, 2083600, 2083650, 2083700, 2083720, 2083740,
    2083750, 2083760};
__device__ __constant__ int c_ACTION[A] = {1, 64, 128, 256, 512, 1024, 2048};

// Block: 256 threads = 4 waves; one wave per batch element.
// Wave layout: lane = fg*16 + d  (fg in 0..3 handles padded fields
// f = fg, fg+4, ..., fg+24; d in 0..15 is the embedding dim).
__global__ __launch_bounds__(256, 4) void gsq_fm_kernel(
    const int* __restrict__ x,            // (B, F)
    const float* __restrict__ emb_table,  // (TV, 16)
    const float* __restrict__ lin_w,      // (TV, 1)
    const float* __restrict__ lin_bias,   // (1,)
    const float* __restrict__ codebooks,  // (6, F, 2048, 16)
    const int* __restrict__ assignments,  // (6, TV)
    const float* __restrict__ arch,       // (F, A)
    const float* __restrict__ gumbel,     // (F, A)
    float* __restrict__ out)              // (B,)
{
    __shared__ float probs_s[FPAD][A];
    __shared__ int gid_s[4][FPAD];

    const int t = threadIdx.x;

    // ---- stage gids for the block's 4 batch elements (128 threads) ----
    if (t < 128) {
        const int e = t >> 5;
        const int fi = t & 31;
        if (fi < FPAD) {
            gid_s[e][fi] = (fi < F)
                ? (x[(blockIdx.x * 4 + e) * F + fi] + c_OFFSETS[fi])
                : 0;
        }
    }

    // ---- per-block probs (28 threads; pad rows are zero) ----
    if (t < FPAD) {
        if (t < F) {
            const int dims = c_FIELD_DIMS[t];
            float z[A];
            float m = -1e30f;
            for (int k = 0; k < A; ++k) {
                bool allowed = (k == 0) ? (dims < 150)
                                        : (5 * c_ACTION[k] <= 2 * dims);
                float logit = allowed ? arch[t * A + k] : -1e9f;
                z[k] = logit + gumbel[t * A + k];  // TEMPERATURE == 1
                m = fmaxf(m, z[k]);
            }
            float ssum = 0.f;
            for (int k = 0; k < A; ++k) {
                z[k] = expf(z[k] - m);  // disallowed -> exactly 0.0f
                ssum += z[k];
            }
            const float inv = 1.f / ssum;
            for (int k = 0; k < A; ++k) probs_s[t][k] = z[k] * inv;
        } else {
            for (int k = 0; k < A; ++k) probs_s[t][k] = 0.f;
        }
    }
    __syncthreads();

    const int lane = t & 63;
    const int fg = lane >> 4;   // field group 0..3
    const int d = lane & 15;    // dim 0..15
    const int e = t >> 6;       // batch sub-index within block
    const int b = blockIdx.x * 4 + e;

    const float linm = (d == 0) ? 1.f : 0.f;

    float s_acc = 0.f;   // sum_f x_emb[b,f,d]   (partial over this fg's fields)
    float q_acc = 0.f;   // sum_f x_emb[b,f,d]^2 (partial)
    float lin_acc = 0.f; // sum_f lin_w[gid]     (partial, d==0 lanes only)

#pragma unroll
    for (int j = 0; j < 7; ++j) {
        const int f = fg + 4 * j;          // 0..27 (26,27 are zero-prob pads)
        const int gid = gid_s[e][f];
        const int fc = (f < F) ? f : 0;    // keep codebook addressing in-bounds
        const float vmask = (f < F) ? 1.f : 0.f;

        float xe = 0.f;
        const float p0 = probs_s[f][0];
        if (p0 != 0.f) {  // exactly-zero for big fields and pads
            xe = p0 * emb_table[gid * DIM + d];
        }
#pragma unroll
        for (int a = 0; a < 6; ++a) {
            const float p = probs_s[f][a + 1];   // exactly 0 for dead actions
            const int code = assignments[a * TV + gid];
            xe = fmaf(p, codebooks[(((a * F) + fc) * 2048 + code) * DIM + d], xe);
        }
        s_acc += xe;
        q_acc = fmaf(xe, xe, q_acc);
        lin_acc = fmaf(vmask * linm, lin_w[gid], lin_acc);
    }

    // ---- reductions (register-only, shfl butterflies) ----
    s_acc += __shfl_xor(s_acc, 16, 64);
    s_acc += __shfl_xor(s_acc, 32, 64);
    q_acc += __shfl_xor(q_acc, 16, 64);
    q_acc += __shfl_xor(q_acc, 32, 64);

    float val = s_acc * s_acc - q_acc;  // identical across the 4 fg copies
    val += __shfl_xor(val, 1, 64);
    val += __shfl_xor(val, 2, 64);
    val += __shfl_xor(val, 4, 64);
    val += __shfl_xor(val, 8, 64);

    lin_acc += __shfl_xor(lin_acc, 1, 64);
    lin_acc += __shfl_xor(lin_acc, 2, 64);
    lin_acc += __shfl_xor(lin_acc, 4, 64);
    lin_acc += __shfl_xor(lin_acc, 8, 64);
    lin_acc += __shfl_xor(lin_acc, 16, 64);
    lin_acc += __shfl_xor(lin_acc, 32, 64);

    if (lane == 0) {
        out[b] = lin_acc + lin_bias[0] + 0.5f * val;
    }
}

extern "C" void kernel_launch(void* const* d_in, const int* in_sizes, int n_in,
                              void* d_out, int out_size, void* d_ws, size_t ws_size,
                              hipStream_t stream) {
    const int*   x           = (const int*)d_in[0];
    const float* emb_table   = (const float*)d_in[1];
    const float* lin_w       = (const float*)d_in[2];
    const float* lin_bias    = (const float*)d_in[3];
    const float* codebooks   = (const float*)d_in[4];
    const int*   assignments = (const int*)d_in[5];
    const float* arch        = (const float*)d_in[6];
    const float* gumbel      = (const float*)d_in[7];
    float* out = (float*)d_out;

    dim3 grid(BATCH / 4);   // 4 batch elements (waves) per block
    dim3 block(256);
    hipLaunchKernelGGL(gsq_fm_kernel, grid, block, 0, stream,
                       x, emb_table, lin_w, lin_bias, codebooks, assignments,
                       arch, gumbel, out);
}

// Round 4
// 16.510 us; speedup vs baseline: 1.5445x; 1.0554x over previous
//
#include <hip/hip_runtime.h>
#include <hip/hip_bf16.h>

#define F 26
#define FPAD 32
#define A 7
#define DIM 16
#define BATCH 4096
#define TV 2083764

__device__ __constant__ int c_FIELD_DIMS[F] = {
    1000000, 500000, 250000, 100000, 100000, 50000, 50000, 10000, 10000,
    5000, 5000, 1000, 1000, 500, 500, 200, 200, 100, 100, 50, 50, 20, 20,
    10, 10, 4};
__device__ __constant__ int c_OFFSETS[F] = {
    0, 1000000, 1500000, 1750000, 1850000, 1950000, 2000000, 2050000,
    2060000, 2070000, 2075000, 2080000, 2081000, 2082000, 2082500, 2083000,
    2083200, 2083400, 2083500, 2083600, 2083650, 2083700, 2083720, 2083740,
    2083750, 2083760};
__device__ __constant__ int c_ACTION[A] = {1, 64, 128, 256, 512, 1024, 2048};

// Block: 256 threads = 4 waves = 2 batch elements (2 waves per batch elem).
// Wave pair h=0,1 splits the 32 (padded) fields 16 ways:
//   lane = sub*8 + dh;  sub = lane>>3 (0..7), dh = lane&7 (dims 2*dh, 2*dh+1)
//   wave h covers fields f = h*8 + sub + 16*j, j = 0,1.
__global__ __launch_bounds__(256, 8) void gsq_fm_kernel(
    const int* __restrict__ x,            // (B, F)
    const float* __restrict__ emb_table,  // (TV, 16)
    const float* __restrict__ lin_w,      // (TV, 1)
    const float* __restrict__ lin_bias,   // (1,)
    const float* __restrict__ codebooks,  // (6, F, 2048, 16)
    const int* __restrict__ assignments,  // (6, TV)
    const float* __restrict__ arch,       // (F, A)
    const float* __restrict__ gumbel,     // (F, A)
    float* __restrict__ out)              // (B,)
{
    __shared__ float probs_s[FPAD][A];
    __shared__ int gid_s[2][FPAD];
    __shared__ float s_red[2][2][8][2];
    __shared__ float q_red[2][2];
    __shared__ float lin_red[2][2];

    const int t = threadIdx.x;

    // ---- stage gids for the block's 2 batch elements (threads 0..63) ----
    if (t < 64) {
        const int e = t >> 5;
        const int fi = t & 31;
        gid_s[e][fi] = (fi < F)
            ? (x[(blockIdx.x * 2 + e) * F + fi] + c_OFFSETS[fi])
            : 0;
    }

    // ---- per-block probs (threads 64..95; pad rows zero) ----
    if (t >= 64 && t < 64 + FPAD) {
        const int f = t - 64;
        if (f < F) {
            const int dims = c_FIELD_DIMS[f];
            float z[A];
            float m = -1e30f;
            for (int k = 0; k < A; ++k) {
                bool allowed = (k == 0) ? (dims < 150)
                                        : (5 * c_ACTION[k] <= 2 * dims);
                float logit = allowed ? arch[f * A + k] : -1e9f;
                z[k] = logit + gumbel[f * A + k];  // TEMPERATURE == 1
                m = fmaxf(m, z[k]);
            }
            float ssum = 0.f;
            for (int k = 0; k < A; ++k) {
                z[k] = expf(z[k] - m);  // disallowed -> exactly 0.0f
                ssum += z[k];
            }
            const float inv = 1.f / ssum;
            for (int k = 0; k < A; ++k) probs_s[f][k] = z[k] * inv;
        } else {
            for (int k = 0; k < A; ++k) probs_s[f][k] = 0.f;
        }
    }
    __syncthreads();

    const int lane = t & 63;
    const int h = (t >> 6) & 1;   // wave within pair
    const int e = t >> 7;         // batch sub-index (0..1)
    const int b = blockIdx.x * 2 + e;
    const int sub = lane >> 3;    // field sub-group 0..7
    const int dh = lane & 7;      // dim pair (dims 2*dh, 2*dh+1)

    float sx = 0.f, sy = 0.f;  // sum_f xe[f, 2dh], xe[f, 2dh+1]
    float q = 0.f;             // sum_{f,d} xe^2 (this lane's share)
    float lin = 0.f;           // lin_w partial (dh==0 lanes only)

#pragma unroll
    for (int j = 0; j < 2; ++j) {
        const int f = h * 8 + sub + 16 * j;   // covers 0..31 over the pair
        const int gid = gid_s[e][f];
        const int fc = (f < F) ? f : 0;       // in-bounds codebook addressing

        float xex = 0.f, xey = 0.f;
        const float p0 = probs_s[f][0];
        if (p0 != 0.f) {  // only small fields; exec-masked per sub-group
            const float2 r = *(const float2*)&emb_table[gid * DIM + 2 * dh];
            xex = p0 * r.x;
            xey = p0 * r.y;
        }
#pragma unroll
        for (int a = 0; a < 6; ++a) {
            const float p = probs_s[f][a + 1];   // exactly 0 for dead actions
            const int code = assignments[a * TV + gid];
            const float2 r = *(const float2*)
                &codebooks[(((a * F) + fc) * 2048 + code) * DIM + 2 * dh];
            xex = fmaf(p, r.x, xex);
            xey = fmaf(p, r.y, xey);
        }
        sx += xex;
        sy += xey;
        q = fmaf(xex, xex, q);
        q = fmaf(xey, xey, q);
        if (dh == 0 && f < F) lin += lin_w[gid];  // mask pads (round-3 bug fix)
    }

    // ---- in-wave reductions ----
    // s: sum across the 8 sub-groups (lane bits 3,4,5)
    sx += __shfl_xor(sx, 8, 64);
    sx += __shfl_xor(sx, 16, 64);
    sx += __shfl_xor(sx, 32, 64);
    sy += __shfl_xor(sy, 8, 64);
    sy += __shfl_xor(sy, 16, 64);
    sy += __shfl_xor(sy, 32, 64);
    // q, lin: full 64-lane butterflies
    q += __shfl_xor(q, 1, 64);
    q += __shfl_xor(q, 2, 64);
    q += __shfl_xor(q, 4, 64);
    q += __shfl_xor(q, 8, 64);
    q += __shfl_xor(q, 16, 64);
    q += __shfl_xor(q, 32, 64);
    lin += __shfl_xor(lin, 1, 64);
    lin += __shfl_xor(lin, 2, 64);
    lin += __shfl_xor(lin, 4, 64);
    lin += __shfl_xor(lin, 8, 64);
    lin += __shfl_xor(lin, 16, 64);
    lin += __shfl_xor(lin, 32, 64);

    if (lane < 8) {
        s_red[e][h][lane][0] = sx;
        s_red[e][h][lane][1] = sy;
    }
    if (lane == 0) {
        q_red[e][h] = q;
        lin_red[e][h] = lin;
    }
    __syncthreads();

    // ---- cross-wave combine (even wave of each pair) ----
    if (h == 0) {
        const int dd = lane & 7;
        const float tx = s_red[e][0][dd][0] + s_red[e][1][dd][0];
        const float ty = s_red[e][0][dd][1] + s_red[e][1][dd][1];
        float val = tx * tx + ty * ty;   // replicated across lane>>3 groups
        val += __shfl_xor(val, 1, 64);
        val += __shfl_xor(val, 2, 64);
        val += __shfl_xor(val, 4, 64);
        if (lane == 0) {
            const float qt = q_red[e][0] + q_red[e][1];
            const float lt = lin_red[e][0] + lin_red[e][1];
            out[b] = lt + lin_bias[0] + 0.5f * (val - qt);
        }
    }
}

extern "C" void kernel_launch(void* const* d_in, const int* in_sizes, int n_in,
                              void* d_out, int out_size, void* d_ws, size_t ws_size,
                              hipStream_t stream) {
    const int*   x           = (const int*)d_in[0];
    const float* emb_table   = (const float*)d_in[1];
    const float* lin_w       = (const float*)d_in[2];
    const float* lin_bias    = (const float*)d_in[3];
    const float* codebooks   = (const float*)d_in[4];
    const int*   assignments = (const int*)d_in[5];
    const float* arch        = (const float*)d_in[6];
    const float* gumbel      = (const float*)d_in[7];
    float* out = (float*)d_out;

    dim3 grid(BATCH / 2);   // 2 batch elements (2 waves each) per block
    dim3 block(256);
    hipLaunchKernelGGL(gsq_fm_kernel, grid, block, 0, stream,
                       x, emb_table, lin_w, lin_bias, codebooks, assignments,
                       arch, gumbel, out);
}

// Round 5
// 16.001 us; speedup vs baseline: 1.5937x; 1.0318x over previous
//
#include <hip/hip_runtime.h>
#include <hip/hip_bf16.h>

#define F 26
#define FPAD 32
#define A 7
#define DIM 16
#define BATCH 4096
#define TV 2083764

__device__ __constant__ int c_OFFSETS[F] = {
    0, 1000000, 1500000, 1750000, 1850000, 1950000, 2000000, 2050000,
    2060000, 2070000, 2075000, 2080000, 2081000, 2082000, 2082500, 2083000,
    2083200, 2083400, 2083500, 2083600, 2083650, 2083700, 2083720, 2083740,
    2083750, 2083760};
__device__ __constant__ int c_FIELD_DIMS[F] = {
    1000000, 500000, 250000, 100000, 100000, 50000, 50000, 10000, 10000,
    5000, 5000, 1000, 1000, 500, 500, 200, 200, 100, 100, 50, 50, 20, 20,
    10, 10, 4};
__device__ __constant__ int c_ACTION[A] = {1, 64, 128, 256, 512, 1024, 2048};
// live codebook-action count per (padded) field: # of a in 1..6 with
// ACTION[a]*2.5 <= dims
__device__ __constant__ int c_K[FPAD] = {
    6, 6, 6, 6, 6, 6, 6, 6, 6, 5, 5, 3, 3, 2, 2, 1,
    1, 0, 0, 0, 0, 0, 0, 0, 0, 0, 0, 0, 0, 0, 0, 0};
// dims < 150 -> full-emb path live
__device__ __constant__ int c_EMB[FPAD] = {
    0, 0, 0, 0, 0, 0, 0, 0, 0, 0, 0, 0, 0, 0, 0, 0,
    0, 1, 1, 1, 1, 1, 1, 1, 1, 1, 0, 0, 0, 0, 0, 0};

// Block: 256 threads = 4 waves; ONE wave per batch element.
// Wave layout: lane = sub*4 + dh; sub = lane>>2 (0..15) owns fields
// f = sub + 16*j (j = 0,1); dh = lane&3 covers dims 4*dh .. 4*dh+3 (float4).
__global__ __launch_bounds__(256, 4) void gsq_fm_kernel(
    const int* __restrict__ x,            // (B, F)
    const float* __restrict__ emb_table,  // (TV, 16)
    const float* __restrict__ lin_w,      // (TV, 1)
    const float* __restrict__ lin_bias,   // (1,)
    const float* __restrict__ codebooks,  // (6, F, 2048, 16)
    const int* __restrict__ assignments,  // (6, TV)
    const float* __restrict__ arch,       // (F, A)
    const float* __restrict__ gumbel,     // (F, A)
    float* __restrict__ out)              // (B,)
{
    __shared__ float probs_s[FPAD][A];
    __shared__ int gid_s[4][FPAD];

    const int t = threadIdx.x;

    // ---- stage gids for the block's 4 batch elements (threads 0..127) ----
    if (t < 128) {
        const int e = t >> 5;
        const int fi = t & 31;
        gid_s[e][fi] = (fi < F)
            ? (x[(blockIdx.x * 4 + e) * F + fi] + c_OFFSETS[fi])
            : 0;
    }

    // ---- per-block probs (threads 128..159; pad rows zero) ----
    if (t >= 128 && t < 128 + FPAD) {
        const int f = t - 128;
        if (f < F) {
            const int dims = c_FIELD_DIMS[f];
            float z[A];
            float m = -1e30f;
            for (int k = 0; k < A; ++k) {
                bool allowed = (k == 0) ? (dims < 150)
                                        : (5 * c_ACTION[k] <= 2 * dims);
                float logit = allowed ? arch[f * A + k] : -1e9f;
                z[k] = logit + gumbel[f * A + k];  // TEMPERATURE == 1
                m = fmaxf(m, z[k]);
            }
            float ssum = 0.f;
            for (int k = 0; k < A; ++k) {
                z[k] = expf(z[k] - m);  // disallowed -> exactly 0.0f
                ssum += z[k];
            }
            const float inv = 1.f / ssum;
            for (int k = 0; k < A; ++k) probs_s[f][k] = z[k] * inv;
        } else {
            for (int k = 0; k < A; ++k) probs_s[f][k] = 0.f;
        }
    }
    __syncthreads();

    const int lane = t & 63;
    const int e = t >> 6;          // wave id = batch sub-index (0..3)
    const int b = blockIdx.x * 4 + e;
    const int sub = lane >> 2;     // field sub-group 0..15
    const int dh = lane & 3;       // dims 4*dh .. 4*dh+3

    float sx = 0.f, sy = 0.f, sz = 0.f, sw = 0.f;  // sum_f xe[f, 4dh+0..3]
    float q = 0.f;     // sum_{f,d} xe^2 (this lane's share)
    float lin = 0.f;   // lin_w partial (dh==0 lanes only)

#pragma unroll
    for (int j = 0; j < 2; ++j) {
        const int f = sub + 16 * j;        // 0..31 (26..31 are dead pads)
        const int gid = gid_s[e][f];
        const int K = c_K[f];              // live codebook-action count
        const int fc = (f < F) ? f : 0;    // in-bounds codebook addressing

        float xx = 0.f, xy = 0.f, xz = 0.f, xw = 0.f;
        if (c_EMB[f]) {  // only 9 tiny fields; their table slice is ~23KB
            const float p0 = probs_s[f][0];
            const float4 r = *(const float4*)&emb_table[gid * DIM + 4 * dh];
            xx = p0 * r.x; xy = p0 * r.y; xz = p0 * r.z; xw = p0 * r.w;
        }
#pragma unroll
        for (int a = 0; a < 6; ++a) {
            if (a < K) {  // exec-masked: dead actions generate NO traffic
                const float p = probs_s[f][a + 1];
                const int code = assignments[a * TV + gid];
                const float4 r = *(const float4*)
                    &codebooks[(((a * F) + fc) * 2048 + code) * DIM + 4 * dh];
                xx = fmaf(p, r.x, xx);
                xy = fmaf(p, r.y, xy);
                xz = fmaf(p, r.z, xz);
                xw = fmaf(p, r.w, xw);
            }
        }
        sx += xx; sy += xy; sz += xz; sw += xw;
        q = fmaf(xx, xx, q);
        q = fmaf(xy, xy, q);
        q = fmaf(xz, xz, q);
        q = fmaf(xw, xw, q);
        if (dh == 0 && f < F) lin += lin_w[gid];
    }

    // ---- in-wave reductions ----
    // s: sum across the 16 sub-groups (lane bits 2..5)
    sx += __shfl_xor(sx, 4, 64);  sx += __shfl_xor(sx, 8, 64);
    sx += __shfl_xor(sx, 16, 64); sx += __shfl_xor(sx, 32, 64);
    sy += __shfl_xor(sy, 4, 64);  sy += __shfl_xor(sy, 8, 64);
    sy += __shfl_xor(sy, 16, 64); sy += __shfl_xor(sy, 32, 64);
    sz += __shfl_xor(sz, 4, 64);  sz += __shfl_xor(sz, 8, 64);
    sz += __shfl_xor(sz, 16, 64); sz += __shfl_xor(sz, 32, 64);
    sw += __shfl_xor(sw, 4, 64);  sw += __shfl_xor(sw, 8, 64);
    sw += __shfl_xor(sw, 16, 64); sw += __shfl_xor(sw, 32, 64);

    // q, lin: full 64-lane butterflies
    q += __shfl_xor(q, 1, 64);  q += __shfl_xor(q, 2, 64);
    q += __shfl_xor(q, 4, 64);  q += __shfl_xor(q, 8, 64);
    q += __shfl_xor(q, 16, 64); q += __shfl_xor(q, 32, 64);
    lin += __shfl_xor(lin, 1, 64);  lin += __shfl_xor(lin, 2, 64);
    lin += __shfl_xor(lin, 4, 64);  lin += __shfl_xor(lin, 8, 64);
    lin += __shfl_xor(lin, 16, 64); lin += __shfl_xor(lin, 32, 64);

    // s^2 dot: per-lane partial over its 4 dims, then sum across dh (bits 0,1)
    float val = sx * sx + sy * sy + sz * sz + sw * sw;
    val += __shfl_xor(val, 1, 64);
    val += __shfl_xor(val, 2, 64);

    if (lane == 0) {
        out[b] = lin + lin_bias[0] + 0.5f * (val - q);
    }
}

extern "C" void kernel_launch(void* const* d_in, const int* in_sizes, int n_in,
                              void* d_out, int out_size, void* d_ws, size_t ws_size,
                              hipStream_t stream) {
    const int*   x           = (const int*)d_in[0];
    const float* emb_table   = (const float*)d_in[1];
    const float* lin_w       = (const float*)d_in[2];
    const float* lin_bias    = (const float*)d_in[3];
    const float* codebooks   = (const float*)d_in[4];
    const int*   assignments = (const int*)d_in[5];
    const float* arch        = (const float*)d_in[6];
    const float* gumbel      = (const float*)d_in[7];
    float* out = (float*)d_out;

    dim3 grid(BATCH / 4);   // 4 batch elements (1 wave each) per block
    dim3 block(256);
    hipLaunchKernelGGL(gsq_fm_kernel, grid, block, 0, stream,
                       x, emb_table, lin_w, lin_bias, codebooks, assignments,
                       arch, gumbel, out);
}